// Round 1
// baseline (476.852 us; speedup 1.0000x reference)
//
#include <hip/hip_runtime.h>

#define NEG 0.2f

__device__ __forceinline__ float lrelu(float v) { return v > 0.f ? v : NEG * v; }

// W1ext[128][68]: cols 0..63 = W1; col 64+j = W1[:, h*32:h*32+32] @ att  (j: 0=src_h0,1=src_h1,2=dst_h0,3=dst_h1)
__global__ void build_w1ext(const float* __restrict__ W1, const float* __restrict__ asrc,
                            const float* __restrict__ adst, float* __restrict__ Wext) {
    int i = blockIdx.x * blockDim.x + threadIdx.x;
    if (i >= 128 * 68) return;
    int k = i / 68, c = i % 68;
    if (c < 64) { Wext[i] = W1[k * 64 + c]; return; }
    int j = c - 64;
    int hh = j & 1;
    const float* att = (j >= 2) ? adst : asrc;
    float s = 0.f;
    for (int d = 0; d < 32; ++d) s += W1[k * 64 + hh * 32 + d] * att[hh * 32 + d];
    Wext[i] = s;
}

// W2ext[64][36]: 0..15 = W_mu, 16..31 = W_ls, 32..35 = attention projection vectors
__global__ void build_w2ext(const float* __restrict__ Wmu, const float* __restrict__ Wls,
                            const float* __restrict__ asmu, const float* __restrict__ admu,
                            const float* __restrict__ asls, const float* __restrict__ adls,
                            float* __restrict__ Wext) {
    int i = blockIdx.x * blockDim.x + threadIdx.x;
    if (i >= 64 * 36) return;
    int k = i / 36, c = i % 36;
    if (c < 16) { Wext[i] = Wmu[k * 16 + c]; return; }
    if (c < 32) { Wext[i] = Wls[k * 16 + (c - 16)]; return; }
    int j = c - 32;
    const float* W = (j < 2) ? Wmu : Wls;
    const float* att = (j == 0) ? asmu : (j == 1) ? admu : (j == 2) ? asls : adls;
    float s = 0.f;
    for (int c2 = 0; c2 < 16; ++c2) s += W[k * 16 + c2] * att[c2];
    Wext[i] = s;
}

// h[N][64] = x @ W1,  a1[N][4] = attention logit pieces
__global__ __launch_bounds__(256) void gemm1(const float* __restrict__ x,
                                             const float* __restrict__ Wext,
                                             float* __restrict__ h, float* __restrict__ a1, int n) {
    __shared__ float xs[16][129];
    __shared__ float Ws[128][68];
    int t = threadIdx.x;
    int row0 = blockIdx.x * 16;
    for (int i = t; i < 128 * 68; i += 256) Ws[i / 68][i % 68] = Wext[i];
    for (int i = t; i < 16 * 128; i += 256) {
        int r = i >> 7, k = i & 127;
        int gr = row0 + r;
        xs[r][k] = (gr < n) ? x[gr * 128 + k] : 0.f;
    }
    __syncthreads();
    int r = t >> 4, c = t & 15;
    float acc0 = 0, acc1 = 0, acc2 = 0, acc3 = 0;
    for (int k = 0; k < 128; ++k) {
        float xv = xs[r][k];
        acc0 += xv * Ws[k][c * 4 + 0];
        acc1 += xv * Ws[k][c * 4 + 1];
        acc2 += xv * Ws[k][c * 4 + 2];
        acc3 += xv * Ws[k][c * 4 + 3];
    }
    int gr = row0 + r;
    if (gr < n) {
        float* hp = &h[gr * 64 + c * 4];
        hp[0] = acc0; hp[1] = acc1; hp[2] = acc2; hp[3] = acc3;
    }
    if (t < 64) {
        int r2 = t >> 2, j = t & 3;
        float a = 0.f;
        for (int k = 0; k < 128; ++k) a += xs[r2][k] * Ws[k][64 + j];
        if (row0 + r2 < n) a1[(row0 + r2) * 4 + j] = a;
    }
}

__global__ void count_deg(const int* __restrict__ dstv, int E, int* __restrict__ deg) {
    int i = blockIdx.x * blockDim.x + threadIdx.x;
    if (i < E) atomicAdd(&deg[dstv[i]], 1);
}

// single-block exclusive scan of deg -> offs[n+1], cursor copy
__global__ __launch_bounds__(1024) void scan_deg(const int* __restrict__ deg, int* __restrict__ offs,
                                                 int* __restrict__ cursor, int n) {
    __shared__ int sums[1024];
    int t = threadIdx.x;
    int per = (n + 1023) >> 10;
    int s0 = t * per, s1 = min(s0 + per, n);
    int s = 0;
    for (int i = s0; i < s1; ++i) s += deg[i];
    sums[t] = s;
    __syncthreads();
    for (int o = 1; o < 1024; o <<= 1) {
        int v = (t >= o) ? sums[t - o] : 0;
        __syncthreads();
        sums[t] += v;
        __syncthreads();
    }
    int base = (t == 0) ? 0 : sums[t - 1];
    for (int i = s0; i < s1; ++i) {
        offs[i] = base;
        cursor[i] = base;
        base += deg[i];
    }
    if (t == 1023) offs[n] = sums[1023];
}

__global__ void scatter_edges(const int* __restrict__ srcv, const int* __restrict__ dstv, int E,
                              int* __restrict__ cursor, int* __restrict__ srcs) {
    int i = blockIdx.x * blockDim.x + threadIdx.x;
    if (i < E) {
        int d = dstv[i];
        int slot = atomicAdd(&cursor[d], 1);
        srcs[slot] = srcv[i];
    }
}

// layer-1 aggregation: one 64-lane wave per node, lane owns channel c (head = c>>5)
__global__ __launch_bounds__(256) void agg1(const float* __restrict__ h, const float* __restrict__ a1,
                                            const int* __restrict__ offs, const int* __restrict__ srcs,
                                            const float* __restrict__ b1, float* __restrict__ h1, int n) {
    int wid = threadIdx.x >> 6, lane = threadIdx.x & 63;
    int node = blockIdx.x * 4 + wid;
    if (node >= n) return;
    int head = lane >> 5;
    float adst = a1[node * 4 + 2 + head];
    float w = __expf(lrelu(a1[node * 4 + head] + adst));   // self loop
    float denom = w;
    float acc = w * h[node * 64 + lane];
    int kb = offs[node], ke = offs[node + 1];
    for (int k = kb; k < ke; ++k) {
        int s = srcs[k];
        float wv = __expf(lrelu(a1[s * 4 + head] + adst));
        denom += wv;
        acc += wv * h[s * 64 + lane];
    }
    float o = acc / denom + b1[lane];
    h1[node * 64 + lane] = o > 0.f ? o : 0.f;
}

// hm[N][16] = h1 @ W_mu, hls[N][16] = h1 @ W_ls, a2[N][4] attention pieces
__global__ __launch_bounds__(256) void gemm2(const float* __restrict__ h1,
                                             const float* __restrict__ Wext,
                                             float* __restrict__ hm, float* __restrict__ hls,
                                             float* __restrict__ a2, int n) {
    __shared__ float hs[16][65];
    __shared__ float Ws[64][36];
    int t = threadIdx.x;
    int row0 = blockIdx.x * 16;
    for (int i = t; i < 64 * 36; i += 256) Ws[i / 36][i % 36] = Wext[i];
    for (int i = t; i < 16 * 64; i += 256) {
        int r = i >> 6, k = i & 63;
        int gr = row0 + r;
        hs[r][k] = (gr < n) ? h1[gr * 64 + k] : 0.f;
    }
    __syncthreads();
    int r = t >> 4, c = t & 15;
    float am = 0, al = 0;
    for (int k = 0; k < 64; ++k) {
        float hv = hs[r][k];
        am += hv * Ws[k][c];
        al += hv * Ws[k][16 + c];
    }
    int gr = row0 + r;
    if (gr < n) {
        hm[gr * 16 + c] = am;
        hls[gr * 16 + c] = al;
    }
    if (t < 64) {
        int r2 = t >> 2, j = t & 3;
        float a = 0.f;
        for (int k = 0; k < 64; ++k) a += hs[r2][k] * Ws[k][32 + j];
        if (row0 + r2 < n) a2[(row0 + r2) * 4 + j] = a;
    }
}

// fused mu+ls aggregation: 16 lanes per node (lane owns channel), 16 nodes per block
__global__ __launch_bounds__(256) void agg2(const float* __restrict__ hm, const float* __restrict__ hls,
                                            const float* __restrict__ a2, const int* __restrict__ offs,
                                            const int* __restrict__ srcs,
                                            const float* __restrict__ bmu, const float* __restrict__ bls,
                                            float* __restrict__ out, int n) {
    int tid = threadIdx.x;
    int node = blockIdx.x * 16 + (tid >> 4);
    int c = tid & 15;
    if (node >= n) return;
    float admu = a2[node * 4 + 1], adls = a2[node * 4 + 3];
    float wmu = __expf(lrelu(a2[node * 4 + 0] + admu));    // self loop
    float wls = __expf(lrelu(a2[node * 4 + 2] + adls));
    float dmu = wmu, dls = wls;
    float amu = wmu * hm[node * 16 + c];
    float als = wls * hls[node * 16 + c];
    int kb = offs[node], ke = offs[node + 1];
    for (int k = kb; k < ke; ++k) {
        int s = srcs[k];
        float w1v = __expf(lrelu(a2[s * 4 + 0] + admu));
        float w2v = __expf(lrelu(a2[s * 4 + 2] + adls));
        dmu += w1v; dls += w2v;
        amu += w1v * hm[s * 16 + c];
        als += w2v * hls[s * 16 + c];
    }
    out[node * 16 + c] = amu / dmu + bmu[c];
    out[(size_t)n * 16 + node * 16 + c] = als / dls + bls[c];
}

extern "C" void kernel_launch(void* const* d_in, const int* in_sizes, int n_in,
                              void* d_out, int out_size, void* d_ws, size_t ws_size,
                              hipStream_t stream) {
    const float* x    = (const float*)d_in[0];
    const int*   ei   = (const int*)d_in[1];
    const float* W1   = (const float*)d_in[2];
    const float* as1  = (const float*)d_in[3];
    const float* ad1  = (const float*)d_in[4];
    const float* b1   = (const float*)d_in[5];
    const float* Wmu  = (const float*)d_in[6];
    const float* asmu = (const float*)d_in[7];
    const float* admu = (const float*)d_in[8];
    const float* bmu  = (const float*)d_in[9];
    const float* Wls  = (const float*)d_in[10];
    const float* asls = (const float*)d_in[11];
    const float* adls = (const float*)d_in[12];
    const float* bls  = (const float*)d_in[13];
    float* out = (float*)d_out;

    int n = in_sizes[0] / 128;
    int E = in_sizes[1] / 2;

    char* ws = (char*)d_ws;
    size_t off = 0;
    auto alloc = [&](size_t b) { size_t p = off; off = (off + b + 255) & ~(size_t)255; return p; };

    float* h    = (float*)(ws + alloc((size_t)n * 64 * 4));
    float* h1   = (float*)(ws + alloc((size_t)n * 64 * 4));
    float* a1   = (float*)(ws + alloc((size_t)n * 4 * 4));
    float* hm   = (float*)(ws + alloc((size_t)n * 16 * 4));
    float* hls  = (float*)(ws + alloc((size_t)n * 16 * 4));
    float* a2   = (float*)(ws + alloc((size_t)n * 4 * 4));
    float* w1e  = (float*)(ws + alloc(128 * 68 * 4));
    float* w2e  = (float*)(ws + alloc(64 * 36 * 4));
    int*   deg    = (int*)(ws + alloc((size_t)n * 4));
    int*   offs   = (int*)(ws + alloc((size_t)(n + 1) * 4));
    int*   cursor = (int*)(ws + alloc((size_t)n * 4));
    int*   srcs   = (int*)(ws + alloc((size_t)E * 4));

    hipMemsetAsync(deg, 0, (size_t)n * 4, stream);
    build_w1ext<<<(128 * 68 + 255) / 256, 256, 0, stream>>>(W1, as1, ad1, w1e);
    build_w2ext<<<(64 * 36 + 255) / 256, 256, 0, stream>>>(Wmu, Wls, asmu, admu, asls, adls, w2e);
    gemm1<<<(n + 15) / 16, 256, 0, stream>>>(x, w1e, h, a1, n);
    count_deg<<<(E + 255) / 256, 256, 0, stream>>>(ei + E, E, deg);
    scan_deg<<<1, 1024, 0, stream>>>(deg, offs, cursor, n);
    scatter_edges<<<(E + 255) / 256, 256, 0, stream>>>(ei, ei + E, E, cursor, srcs);
    agg1<<<(n + 3) / 4, 256, 0, stream>>>(h, a1, offs, srcs, b1, h1, n);
    gemm2<<<(n + 15) / 16, 256, 0, stream>>>(h1, w2e, hm, hls, a2, n);
    agg2<<<(n + 15) / 16, 256, 0, stream>>>(hm, hls, a2, offs, srcs, bmu, bls, out, n);
}

// Round 2
// 371.180 us; speedup vs baseline: 1.2847x; 1.2847x over previous
//
#include <hip/hip_runtime.h>

#define NEG 0.2f

__device__ __forceinline__ float lrelu(float v) { return v > 0.f ? v : NEG * v; }

// W1ext[128][68]: cols 0..63 = W1; col 64+j = W1[:, h*32:h*32+32] @ att  (j: 0=src_h0,1=src_h1,2=dst_h0,3=dst_h1)
__global__ void build_w1ext(const float* __restrict__ W1, const float* __restrict__ asrc,
                            const float* __restrict__ adst, float* __restrict__ Wext) {
    int i = blockIdx.x * blockDim.x + threadIdx.x;
    if (i >= 128 * 68) return;
    int k = i / 68, c = i % 68;
    if (c < 64) { Wext[i] = W1[k * 64 + c]; return; }
    int j = c - 64;
    int hh = j & 1;
    const float* att = (j >= 2) ? adst : asrc;
    float s = 0.f;
    for (int d = 0; d < 32; ++d) s += W1[k * 64 + hh * 32 + d] * att[hh * 32 + d];
    Wext[i] = s;
}

// W2ext[64][36]: 0..15 = W_mu, 16..31 = W_ls, 32..35 = attention projection vectors
__global__ void build_w2ext(const float* __restrict__ Wmu, const float* __restrict__ Wls,
                            const float* __restrict__ asmu, const float* __restrict__ admu,
                            const float* __restrict__ asls, const float* __restrict__ adls,
                            float* __restrict__ Wext) {
    int i = blockIdx.x * blockDim.x + threadIdx.x;
    if (i >= 64 * 36) return;
    int k = i / 36, c = i % 36;
    if (c < 16) { Wext[i] = Wmu[k * 16 + c]; return; }
    if (c < 32) { Wext[i] = Wls[k * 16 + (c - 16)]; return; }
    int j = c - 32;
    const float* W = (j < 2) ? Wmu : Wls;
    const float* att = (j == 0) ? asmu : (j == 1) ? admu : (j == 2) ? asls : adls;
    float s = 0.f;
    for (int c2 = 0; c2 < 16; ++c2) s += W[k * 16 + c2] * att[c2];
    Wext[i] = s;
}

// h[N][64] = x @ W1,  a1[N][4] = attention logit pieces
__global__ __launch_bounds__(256) void gemm1(const float* __restrict__ x,
                                             const float* __restrict__ Wext,
                                             float* __restrict__ h, float* __restrict__ a1, int n) {
    __shared__ float xs[16][129];
    __shared__ float Ws[128][68];
    int t = threadIdx.x;
    int row0 = blockIdx.x * 16;
    for (int i = t; i < 128 * 68; i += 256) Ws[i / 68][i % 68] = Wext[i];
    for (int i = t; i < 16 * 128; i += 256) {
        int r = i >> 7, k = i & 127;
        int gr = row0 + r;
        xs[r][k] = (gr < n) ? x[gr * 128 + k] : 0.f;
    }
    __syncthreads();
    int r = t >> 4, c = t & 15;
    float acc0 = 0, acc1 = 0, acc2 = 0, acc3 = 0;
    for (int k = 0; k < 128; ++k) {
        float xv = xs[r][k];
        acc0 += xv * Ws[k][c * 4 + 0];
        acc1 += xv * Ws[k][c * 4 + 1];
        acc2 += xv * Ws[k][c * 4 + 2];
        acc3 += xv * Ws[k][c * 4 + 3];
    }
    int gr = row0 + r;
    if (gr < n) {
        float* hp = &h[gr * 64 + c * 4];
        hp[0] = acc0; hp[1] = acc1; hp[2] = acc2; hp[3] = acc3;
    }
    if (t < 64) {
        int r2 = t >> 2, j = t & 3;
        float a = 0.f;
        for (int k = 0; k < 128; ++k) a += xs[r2][k] * Ws[k][64 + j];
        if (row0 + r2 < n) a1[(row0 + r2) * 4 + j] = a;
    }
}

__global__ void count_deg(const int* __restrict__ dstv, int E, int* __restrict__ deg) {
    int i = blockIdx.x * blockDim.x + threadIdx.x;
    if (i < E) atomicAdd(&deg[dstv[i]], 1);
}

// ---- 3-phase parallel scan of deg -> offs/cursor ----
// A: per-block (256 nodes) degree sums
__global__ __launch_bounds__(256) void block_sums(const int* __restrict__ deg, int n,
                                                  int* __restrict__ bsums) {
    int i = blockIdx.x * 256 + threadIdx.x;
    int v = (i < n) ? deg[i] : 0;
    for (int o = 32; o > 0; o >>= 1) v += __shfl_down(v, o, 64);
    __shared__ int ws[4];
    if ((threadIdx.x & 63) == 0) ws[threadIdx.x >> 6] = v;
    __syncthreads();
    if (threadIdx.x == 0) bsums[blockIdx.x] = ws[0] + ws[1] + ws[2] + ws[3];
}

// B: exclusive scan of nb (<=256) block sums, in place
__global__ __launch_bounds__(256) void scan_bsums(int* __restrict__ bsums, int nb) {
    __shared__ int s[256];
    int t = threadIdx.x;
    int v = (t < nb) ? bsums[t] : 0;
    s[t] = v;
    __syncthreads();
    for (int o = 1; o < 256; o <<= 1) {
        int u = (t >= o) ? s[t - o] : 0;
        __syncthreads();
        s[t] += u;
        __syncthreads();
    }
    if (t < nb) bsums[t] = s[t] - v;   // exclusive
}

// C: per-block exclusive scan + block base -> offs, cursor
__global__ __launch_bounds__(256) void write_offs(const int* __restrict__ deg,
                                                  const int* __restrict__ bsums, int n,
                                                  int* __restrict__ offs, int* __restrict__ cursor) {
    int t = threadIdx.x;
    int i = blockIdx.x * 256 + t;
    int v = (i < n) ? deg[i] : 0;
    __shared__ int s[256];
    s[t] = v;
    __syncthreads();
    for (int o = 1; o < 256; o <<= 1) {
        int u = (t >= o) ? s[t - o] : 0;
        __syncthreads();
        s[t] += u;
        __syncthreads();
    }
    int excl = s[t] - v + bsums[blockIdx.x];
    if (i < n) { offs[i] = excl; cursor[i] = excl; }
    if (i == n - 1) offs[n] = excl + v;
}

__global__ void scatter_edges(const int* __restrict__ srcv, const int* __restrict__ dstv, int E,
                              int* __restrict__ cursor, int* __restrict__ srcs) {
    int i = blockIdx.x * blockDim.x + threadIdx.x;
    if (i < E) {
        int d = dstv[i];
        int slot = atomicAdd(&cursor[d], 1);
        srcs[slot] = srcv[i];
    }
}

// layer-1 aggregation: one 64-lane wave per node, lane owns channel c (head = c>>5)
__global__ __launch_bounds__(256) void agg1(const float* __restrict__ h, const float* __restrict__ a1,
                                            const int* __restrict__ offs, const int* __restrict__ srcs,
                                            const float* __restrict__ b1, float* __restrict__ h1, int n) {
    int wid = threadIdx.x >> 6, lane = threadIdx.x & 63;
    int node = blockIdx.x * 4 + wid;
    if (node >= n) return;
    int head = lane >> 5;
    float adst = a1[node * 4 + 2 + head];
    float w = __expf(lrelu(a1[node * 4 + head] + adst));   // self loop
    float denom = w;
    float acc = w * h[node * 64 + lane];
    int kb = offs[node], ke = offs[node + 1];
    for (int k = kb; k < ke; ++k) {
        int s = srcs[k];
        float wv = __expf(lrelu(a1[s * 4 + head] + adst));
        denom += wv;
        acc += wv * h[s * 64 + lane];
    }
    float o = acc / denom + b1[lane];
    h1[node * 64 + lane] = o > 0.f ? o : 0.f;
}

// hm[N][16] = h1 @ W_mu, hls[N][16] = h1 @ W_ls, a2[N][4] attention pieces
__global__ __launch_bounds__(256) void gemm2(const float* __restrict__ h1,
                                             const float* __restrict__ Wext,
                                             float* __restrict__ hm, float* __restrict__ hls,
                                             float* __restrict__ a2, int n) {
    __shared__ float hs[16][65];
    __shared__ float Ws[64][36];
    int t = threadIdx.x;
    int row0 = blockIdx.x * 16;
    for (int i = t; i < 64 * 36; i += 256) Ws[i / 36][i % 36] = Wext[i];
    for (int i = t; i < 16 * 64; i += 256) {
        int r = i >> 6, k = i & 63;
        int gr = row0 + r;
        hs[r][k] = (gr < n) ? h1[gr * 64 + k] : 0.f;
    }
    __syncthreads();
    int r = t >> 4, c = t & 15;
    float am = 0, al = 0;
    for (int k = 0; k < 64; ++k) {
        float hv = hs[r][k];
        am += hv * Ws[k][c];
        al += hv * Ws[k][16 + c];
    }
    int gr = row0 + r;
    if (gr < n) {
        hm[gr * 16 + c] = am;
        hls[gr * 16 + c] = al;
    }
    if (t < 64) {
        int r2 = t >> 2, j = t & 3;
        float a = 0.f;
        for (int k = 0; k < 64; ++k) a += hs[r2][k] * Ws[k][32 + j];
        if (row0 + r2 < n) a2[(row0 + r2) * 4 + j] = a;
    }
}

// fused mu+ls aggregation: 16 lanes per node (lane owns channel), 16 nodes per block
__global__ __launch_bounds__(256) void agg2(const float* __restrict__ hm, const float* __restrict__ hls,
                                            const float* __restrict__ a2, const int* __restrict__ offs,
                                            const int* __restrict__ srcs,
                                            const float* __restrict__ bmu, const float* __restrict__ bls,
                                            float* __restrict__ out, int n) {
    int tid = threadIdx.x;
    int node = blockIdx.x * 16 + (tid >> 4);
    int c = tid & 15;
    if (node >= n) return;
    float admu = a2[node * 4 + 1], adls = a2[node * 4 + 3];
    float wmu = __expf(lrelu(a2[node * 4 + 0] + admu));    // self loop
    float wls = __expf(lrelu(a2[node * 4 + 2] + adls));
    float dmu = wmu, dls = wls;
    float amu = wmu * hm[node * 16 + c];
    float als = wls * hls[node * 16 + c];
    int kb = offs[node], ke = offs[node + 1];
    for (int k = kb; k < ke; ++k) {
        int s = srcs[k];
        float w1v = __expf(lrelu(a2[s * 4 + 0] + admu));
        float w2v = __expf(lrelu(a2[s * 4 + 2] + adls));
        dmu += w1v; dls += w2v;
        amu += w1v * hm[s * 16 + c];
        als += w2v * hls[s * 16 + c];
    }
    out[node * 16 + c] = amu / dmu + bmu[c];
    out[(size_t)n * 16 + node * 16 + c] = als / dls + bls[c];
}

extern "C" void kernel_launch(void* const* d_in, const int* in_sizes, int n_in,
                              void* d_out, int out_size, void* d_ws, size_t ws_size,
                              hipStream_t stream) {
    const float* x    = (const float*)d_in[0];
    const int*   ei   = (const int*)d_in[1];
    const float* W1   = (const float*)d_in[2];
    const float* as1  = (const float*)d_in[3];
    const float* ad1  = (const float*)d_in[4];
    const float* b1   = (const float*)d_in[5];
    const float* Wmu  = (const float*)d_in[6];
    const float* asmu = (const float*)d_in[7];
    const float* admu = (const float*)d_in[8];
    const float* bmu  = (const float*)d_in[9];
    const float* Wls  = (const float*)d_in[10];
    const float* asls = (const float*)d_in[11];
    const float* adls = (const float*)d_in[12];
    const float* bls  = (const float*)d_in[13];
    float* out = (float*)d_out;

    int n = in_sizes[0] / 128;
    int E = in_sizes[1] / 2;

    char* ws = (char*)d_ws;
    size_t off = 0;
    auto alloc = [&](size_t b) { size_t p = off; off = (off + b + 255) & ~(size_t)255; return p; };

    float* h    = (float*)(ws + alloc((size_t)n * 64 * 4));
    float* h1   = (float*)(ws + alloc((size_t)n * 64 * 4));
    float* a1   = (float*)(ws + alloc((size_t)n * 4 * 4));
    float* hm   = (float*)(ws + alloc((size_t)n * 16 * 4));
    float* hls  = (float*)(ws + alloc((size_t)n * 16 * 4));
    float* a2   = (float*)(ws + alloc((size_t)n * 4 * 4));
    float* w1e  = (float*)(ws + alloc(128 * 68 * 4));
    float* w2e  = (float*)(ws + alloc(64 * 36 * 4));
    int*   deg    = (int*)(ws + alloc((size_t)n * 4));
    int*   offs   = (int*)(ws + alloc((size_t)(n + 1) * 4));
    int*   cursor = (int*)(ws + alloc((size_t)n * 4));
    int*   srcs   = (int*)(ws + alloc((size_t)E * 4));
    int*   bsums  = (int*)(ws + alloc(1024 * 4));

    int nb = (n + 255) / 256;   // 196 for n=50000 (fits single scan block)

    hipMemsetAsync(deg, 0, (size_t)n * 4, stream);
    build_w1ext<<<(128 * 68 + 255) / 256, 256, 0, stream>>>(W1, as1, ad1, w1e);
    build_w2ext<<<(64 * 36 + 255) / 256, 256, 0, stream>>>(Wmu, Wls, asmu, admu, asls, adls, w2e);
    gemm1<<<(n + 15) / 16, 256, 0, stream>>>(x, w1e, h, a1, n);
    count_deg<<<(E + 255) / 256, 256, 0, stream>>>(ei + E, E, deg);
    block_sums<<<nb, 256, 0, stream>>>(deg, n, bsums);
    scan_bsums<<<1, 256, 0, stream>>>(bsums, nb);
    write_offs<<<nb, 256, 0, stream>>>(deg, bsums, n, offs, cursor);
    scatter_edges<<<(E + 255) / 256, 256, 0, stream>>>(ei, ei + E, E, cursor, srcs);
    agg1<<<(n + 3) / 4, 256, 0, stream>>>(h, a1, offs, srcs, b1, h1, n);
    gemm2<<<(n + 15) / 16, 256, 0, stream>>>(h1, w2e, hm, hls, a2, n);
    agg2<<<(n + 15) / 16, 256, 0, stream>>>(hm, hls, a2, offs, srcs, bmu, bls, out, n);
}

// Round 3
// 334.500 us; speedup vs baseline: 1.4256x; 1.1097x over previous
//
#include <hip/hip_runtime.h>

#define NEG 0.2f

__device__ __forceinline__ float lrelu(float v) { return v > 0.f ? v : NEG * v; }

__device__ __forceinline__ unsigned short f2bf(float f) {
    unsigned u = __float_as_uint(f);
    unsigned r = (u + 0x7FFF + ((u >> 16) & 1)) >> 16;   // RNE
    return (unsigned short)r;
}
__device__ __forceinline__ float bf_lo(unsigned v) { return __uint_as_float(v << 16); }
__device__ __forceinline__ float bf_hi(unsigned v) { return __uint_as_float(v & 0xffff0000u); }

// W1ext[128][68]: cols 0..63 = W1; col 64+j = W1[:, h*32:h*32+32] @ att  (j: 0=src_h0,1=src_h1,2=dst_h0,3=dst_h1)
__global__ void build_w1ext(const float* __restrict__ W1, const float* __restrict__ asrc,
                            const float* __restrict__ adst, float* __restrict__ Wext) {
    int i = blockIdx.x * blockDim.x + threadIdx.x;
    if (i >= 128 * 68) return;
    int k = i / 68, c = i % 68;
    if (c < 64) { Wext[i] = W1[k * 64 + c]; return; }
    int j = c - 64;
    int hh = j & 1;
    const float* att = (j >= 2) ? adst : asrc;
    float s = 0.f;
    for (int d = 0; d < 32; ++d) s += W1[k * 64 + hh * 32 + d] * att[hh * 32 + d];
    Wext[i] = s;
}

// W2ext[64][36]: 0..15 = W_mu, 16..31 = W_ls, 32..35 = attention projection vectors
__global__ void build_w2ext(const float* __restrict__ Wmu, const float* __restrict__ Wls,
                            const float* __restrict__ asmu, const float* __restrict__ admu,
                            const float* __restrict__ asls, const float* __restrict__ adls,
                            float* __restrict__ Wext) {
    int i = blockIdx.x * blockDim.x + threadIdx.x;
    if (i >= 64 * 36) return;
    int k = i / 36, c = i % 36;
    if (c < 16) { Wext[i] = Wmu[k * 16 + c]; return; }
    if (c < 32) { Wext[i] = Wls[k * 16 + (c - 16)]; return; }
    int j = c - 32;
    const float* W = (j < 2) ? Wmu : Wls;
    const float* att = (j == 0) ? asmu : (j == 1) ? admu : (j == 2) ? asls : adls;
    float s = 0.f;
    for (int c2 = 0; c2 < 16; ++c2) s += W[k * 16 + c2] * att[c2];
    Wext[i] = s;
}

// h32[N][32] = packed bf16x2 of x @ W1,  a1[N][4] = attention logit pieces (f32)
__global__ __launch_bounds__(256) void gemm1(const float* __restrict__ x,
                                             const float* __restrict__ Wext,
                                             unsigned* __restrict__ h32, float* __restrict__ a1, int n) {
    __shared__ float xs[16][129];
    __shared__ float Ws[128][68];
    int t = threadIdx.x;
    int row0 = blockIdx.x * 16;
    for (int i = t; i < 128 * 68; i += 256) Ws[i / 68][i % 68] = Wext[i];
    for (int i = t; i < 16 * 128; i += 256) {
        int r = i >> 7, k = i & 127;
        int gr = row0 + r;
        xs[r][k] = (gr < n) ? x[gr * 128 + k] : 0.f;
    }
    __syncthreads();
    int r = t >> 4, c = t & 15;
    float acc0 = 0, acc1 = 0, acc2 = 0, acc3 = 0;
    for (int k = 0; k < 128; ++k) {
        float xv = xs[r][k];
        acc0 += xv * Ws[k][c * 4 + 0];
        acc1 += xv * Ws[k][c * 4 + 1];
        acc2 += xv * Ws[k][c * 4 + 2];
        acc3 += xv * Ws[k][c * 4 + 3];
    }
    int gr = row0 + r;
    if (gr < n) {
        unsigned p0 = ((unsigned)f2bf(acc1) << 16) | f2bf(acc0);
        unsigned p1 = ((unsigned)f2bf(acc3) << 16) | f2bf(acc2);
        *(uint2*)&h32[gr * 32 + c * 2] = make_uint2(p0, p1);
    }
    if (t < 64) {
        int r2 = t >> 2, j = t & 3;
        float a = 0.f;
        for (int k = 0; k < 128; ++k) a += xs[r2][k] * Ws[k][64 + j];
        if (row0 + r2 < n) a1[(row0 + r2) * 4 + j] = a;
    }
}

__global__ void count_deg(const int* __restrict__ dstv, int E, int* __restrict__ deg) {
    int i = blockIdx.x * blockDim.x + threadIdx.x;
    if (i < E) atomicAdd(&deg[dstv[i]], 1);
}

// ---- 3-phase parallel scan of deg -> offs/cursor ----
__global__ __launch_bounds__(256) void block_sums(const int* __restrict__ deg, int n,
                                                  int* __restrict__ bsums) {
    int i = blockIdx.x * 256 + threadIdx.x;
    int v = (i < n) ? deg[i] : 0;
    for (int o = 32; o > 0; o >>= 1) v += __shfl_down(v, o, 64);
    __shared__ int ws[4];
    if ((threadIdx.x & 63) == 0) ws[threadIdx.x >> 6] = v;
    __syncthreads();
    if (threadIdx.x == 0) bsums[blockIdx.x] = ws[0] + ws[1] + ws[2] + ws[3];
}

__global__ __launch_bounds__(256) void scan_bsums(int* __restrict__ bsums, int nb) {
    __shared__ int s[256];
    int t = threadIdx.x;
    int v = (t < nb) ? bsums[t] : 0;
    s[t] = v;
    __syncthreads();
    for (int o = 1; o < 256; o <<= 1) {
        int u = (t >= o) ? s[t - o] : 0;
        __syncthreads();
        s[t] += u;
        __syncthreads();
    }
    if (t < nb) bsums[t] = s[t] - v;   // exclusive
}

__global__ __launch_bounds__(256) void write_offs(const int* __restrict__ deg,
                                                  const int* __restrict__ bsums, int n,
                                                  int* __restrict__ offs, int* __restrict__ cursor) {
    int t = threadIdx.x;
    int i = blockIdx.x * 256 + t;
    int v = (i < n) ? deg[i] : 0;
    __shared__ int s[256];
    s[t] = v;
    __syncthreads();
    for (int o = 1; o < 256; o <<= 1) {
        int u = (t >= o) ? s[t - o] : 0;
        __syncthreads();
        s[t] += u;
        __syncthreads();
    }
    int excl = s[t] - v + bsums[blockIdx.x];
    if (i < n) { offs[i] = excl; cursor[i] = excl; }
    if (i == n - 1) offs[n] = excl + v;
}

__global__ void scatter_edges(const int* __restrict__ srcv, const int* __restrict__ dstv, int E,
                              int* __restrict__ cursor, int* __restrict__ srcs) {
    int i = blockIdx.x * blockDim.x + threadIdx.x;
    if (i < E) {
        int d = dstv[i];
        int slot = atomicAdd(&cursor[d], 1);
        srcs[slot] = srcv[i];
    }
}

// layer-1 aggregation: one 64-lane wave per node.
// lanes 0..31 process even edges, 32..63 odd edges; lane owns channels 2l,2l+1 (one u32).
__global__ __launch_bounds__(256) void agg1(const unsigned* __restrict__ h32, const float* __restrict__ a1,
                                            const int* __restrict__ offs, const int* __restrict__ srcs,
                                            const float* __restrict__ b1, float* __restrict__ h1, int n) {
    int wid = threadIdx.x >> 6, lane = threadIdx.x & 63;
    int node = blockIdx.x * 4 + wid;
    if (node >= n) return;
    int half = lane >> 5;
    int l = lane & 31;          // channel pair: 2l, 2l+1
    int head = l >> 4;
    float adst = a1[node * 4 + 2 + head];
    float acc0 = 0.f, acc1 = 0.f, denom = 0.f;
    if (half == 0) {            // self loop on low half
        float w = __expf(lrelu(a1[node * 4 + head] + adst));
        unsigned hv = h32[node * 32 + l];
        acc0 = w * bf_lo(hv); acc1 = w * bf_hi(hv);
        denom = w;
    }
    int kb = offs[node], ke = offs[node + 1];
    for (int k = kb + half; k < ke; k += 2) {
        int s = srcs[k];
        float wv = __expf(lrelu(a1[s * 4 + head] + adst));
        unsigned hv = h32[s * 32 + l];
        denom += wv;
        acc0 += wv * bf_lo(hv);
        acc1 += wv * bf_hi(hv);
    }
    acc0  += __shfl(acc0,  lane ^ 32, 64);
    acc1  += __shfl(acc1,  lane ^ 32, 64);
    denom += __shfl(denom, lane ^ 32, 64);
    if (half == 0) {
        float o0 = acc0 / denom + b1[2 * l];
        float o1 = acc1 / denom + b1[2 * l + 1];
        *(float2*)&h1[node * 64 + 2 * l] = make_float2(fmaxf(o0, 0.f), fmaxf(o1, 0.f));
    }
}

// hml[N][16] = packed bf16x2 (lo=mu, hi=ls) of h1 @ {W_mu,W_ls}, a2[N][4] logit pieces
__global__ __launch_bounds__(256) void gemm2(const float* __restrict__ h1,
                                             const float* __restrict__ Wext,
                                             unsigned* __restrict__ hml, float* __restrict__ a2, int n) {
    __shared__ float hs[16][65];
    __shared__ float Ws[64][36];
    int t = threadIdx.x;
    int row0 = blockIdx.x * 16;
    for (int i = t; i < 64 * 36; i += 256) Ws[i / 36][i % 36] = Wext[i];
    for (int i = t; i < 16 * 64; i += 256) {
        int r = i >> 6, k = i & 63;
        int gr = row0 + r;
        hs[r][k] = (gr < n) ? h1[gr * 64 + k] : 0.f;
    }
    __syncthreads();
    int r = t >> 4, c = t & 15;
    float am = 0, al = 0;
    for (int k = 0; k < 64; ++k) {
        float hv = hs[r][k];
        am += hv * Ws[k][c];
        al += hv * Ws[k][16 + c];
    }
    int gr = row0 + r;
    if (gr < n) hml[gr * 16 + c] = ((unsigned)f2bf(al) << 16) | f2bf(am);
    if (t < 64) {
        int r2 = t >> 2, j = t & 3;
        float a = 0.f;
        for (int k = 0; k < 64; ++k) a += hs[r2][k] * Ws[k][32 + j];
        if (row0 + r2 < n) a2[(row0 + r2) * 4 + j] = a;
    }
}

// fused mu+ls aggregation: 32 lanes per node (two 16-lane halves over even/odd edges), 8 nodes/block
__global__ __launch_bounds__(256) void agg2(const unsigned* __restrict__ hml,
                                            const float* __restrict__ a2, const int* __restrict__ offs,
                                            const int* __restrict__ srcs,
                                            const float* __restrict__ bmu, const float* __restrict__ bls,
                                            float* __restrict__ out, int n) {
    int grp = threadIdx.x >> 5;
    int node = blockIdx.x * 8 + grp;
    if (node >= n) return;
    int lane32 = threadIdx.x & 31;
    int half = lane32 >> 4;
    int c = lane32 & 15;
    float admu = a2[node * 4 + 1], adls = a2[node * 4 + 3];
    float amu = 0.f, als = 0.f, dmu = 0.f, dls = 0.f;
    if (half == 0) {            // self loop
        float wmu = __expf(lrelu(a2[node * 4 + 0] + admu));
        float wls = __expf(lrelu(a2[node * 4 + 2] + adls));
        unsigned hv = hml[node * 16 + c];
        amu = wmu * bf_lo(hv); als = wls * bf_hi(hv);
        dmu = wmu; dls = wls;
    }
    int kb = offs[node], ke = offs[node + 1];
    for (int k = kb + half; k < ke; k += 2) {
        int s = srcs[k];
        float4 av = *(const float4*)&a2[s * 4];
        float w1v = __expf(lrelu(av.x + admu));
        float w2v = __expf(lrelu(av.z + adls));
        unsigned hv = hml[s * 16 + c];
        dmu += w1v; dls += w2v;
        amu += w1v * bf_lo(hv);
        als += w2v * bf_hi(hv);
    }
    amu += __shfl_xor(amu, 16, 64);
    als += __shfl_xor(als, 16, 64);
    dmu += __shfl_xor(dmu, 16, 64);
    dls += __shfl_xor(dls, 16, 64);
    if (half == 0) {
        out[node * 16 + c] = amu / dmu + bmu[c];
        out[(size_t)n * 16 + node * 16 + c] = als / dls + bls[c];
    }
}

extern "C" void kernel_launch(void* const* d_in, const int* in_sizes, int n_in,
                              void* d_out, int out_size, void* d_ws, size_t ws_size,
                              hipStream_t stream) {
    const float* x    = (const float*)d_in[0];
    const int*   ei   = (const int*)d_in[1];
    const float* W1   = (const float*)d_in[2];
    const float* as1  = (const float*)d_in[3];
    const float* ad1  = (const float*)d_in[4];
    const float* b1   = (const float*)d_in[5];
    const float* Wmu  = (const float*)d_in[6];
    const float* asmu = (const float*)d_in[7];
    const float* admu = (const float*)d_in[8];
    const float* bmu  = (const float*)d_in[9];
    const float* Wls  = (const float*)d_in[10];
    const float* asls = (const float*)d_in[11];
    const float* adls = (const float*)d_in[12];
    const float* bls  = (const float*)d_in[13];
    float* out = (float*)d_out;

    int n = in_sizes[0] / 128;
    int E = in_sizes[1] / 2;

    char* ws = (char*)d_ws;
    size_t off = 0;
    auto alloc = [&](size_t b) { size_t p = off; off = (off + b + 255) & ~(size_t)255; return p; };

    unsigned* h32 = (unsigned*)(ws + alloc((size_t)n * 32 * 4));
    float*    h1  = (float*)(ws + alloc((size_t)n * 64 * 4));
    float*    a1  = (float*)(ws + alloc((size_t)n * 4 * 4));
    unsigned* hml = (unsigned*)(ws + alloc((size_t)n * 16 * 4));
    float*    a2  = (float*)(ws + alloc((size_t)n * 4 * 4));
    float*    w1e = (float*)(ws + alloc(128 * 68 * 4));
    float*    w2e = (float*)(ws + alloc(64 * 36 * 4));
    int*   deg    = (int*)(ws + alloc((size_t)n * 4));
    int*   offs   = (int*)(ws + alloc((size_t)(n + 1) * 4));
    int*   cursor = (int*)(ws + alloc((size_t)n * 4));
    int*   srcs   = (int*)(ws + alloc((size_t)E * 4));
    int*   bsums  = (int*)(ws + alloc(1024 * 4));

    int nb = (n + 255) / 256;

    hipMemsetAsync(deg, 0, (size_t)n * 4, stream);
    build_w1ext<<<(128 * 68 + 255) / 256, 256, 0, stream>>>(W1, as1, ad1, w1e);
    build_w2ext<<<(64 * 36 + 255) / 256, 256, 0, stream>>>(Wmu, Wls, asmu, admu, asls, adls, w2e);
    gemm1<<<(n + 15) / 16, 256, 0, stream>>>(x, w1e, h32, a1, n);
    count_deg<<<(E + 255) / 256, 256, 0, stream>>>(ei + E, E, deg);
    block_sums<<<nb, 256, 0, stream>>>(deg, n, bsums);
    scan_bsums<<<1, 256, 0, stream>>>(bsums, nb);
    write_offs<<<nb, 256, 0, stream>>>(deg, bsums, n, offs, cursor);
    scatter_edges<<<(E + 255) / 256, 256, 0, stream>>>(ei, ei + E, E, cursor, srcs);
    agg1<<<(n + 3) / 4, 256, 0, stream>>>(h32, a1, offs, srcs, b1, h1, n);
    gemm2<<<(n + 15) / 16, 256, 0, stream>>>(h1, w2e, hml, a2, n);
    agg2<<<(n + 7) / 8, 256, 0, stream>>>(hml, a2, offs, srcs, bmu, bls, out, n);
}